// Round 3
// baseline (824.021 us; speedup 1.0000x reference)
//
#include <hip/hip_runtime.h>

#define TILE 64
#define HALO 5
#define KSIZE 11
#define IN_TILE (TILE + 2 * HALO)   // 74
#define LDS_STRIDE 76               // rows 16B-aligned
#define IMG 1024

__device__ __forceinline__ float4 fma4(float w, float4 a, float4 c) {
    return make_float4(fmaf(w, a.x, c.x), fmaf(w, a.y, c.y),
                       fmaf(w, a.z, c.z), fmaf(w, a.w, c.w));
}

__global__ __launch_bounds__(256)
void conv11_tile_kernel(const float* __restrict__ x,
                        const float* __restrict__ w,
                        float* __restrict__ out) {
    __shared__ float tile[IN_TILE * LDS_STRIDE];

    const int tid  = threadIdx.x;
    const int lane = tid & 63;
    const int wid  = tid >> 6;
    const int tx   = tid & 15;       // 16 threads across
    const int ty   = tid >> 4;       // 16 threads down
    const int tile_x0 = blockIdx.x * TILE;
    const int tile_y0 = blockIdx.y * TILE;
    const float* xb = x + (size_t)blockIdx.z * IMG * IMG;

    // ---- stage 74x74 (zero halo) into LDS: wave-per-row stripes, no divides
    for (int r = wid; r < IN_TILE; r += 4) {
        const int gy = tile_y0 + r - HALO;
        const bool rowok = (unsigned)gy < IMG;
        const int gx0 = tile_x0 - HALO + lane;
        float v0 = 0.0f;
        if (rowok && (unsigned)gx0 < IMG) v0 = xb[(size_t)gy * IMG + gx0];
        tile[r * LDS_STRIDE + lane] = v0;
        if (lane < IN_TILE - 64) {           // cols 64..73
            const int gx1 = gx0 + 64;
            float v1 = 0.0f;
            if (rowok && (unsigned)gx1 < IMG) v1 = xb[(size_t)gy * IMG + gx1];
            tile[r * LDS_STRIDE + lane + 64] = v1;
        }
    }
    __syncthreads();

    // ---- 4x4 outputs per thread; all values in NAMED registers (no arrays)
    float4 acc0 = make_float4(0,0,0,0);
    float4 acc1 = acc0, acc2 = acc0, acc3 = acc0;
    const int ly = ty * 4, lx = tx * 4;

    #pragma unroll
    for (int iy = 0; iy < 14; ++iy) {
        // 16 consecutive floats of one LDS row: 4x ds_read_b128,
        // contiguous slots per 16-lane group -> 2-way (free)
        const float4* rp = (const float4*)&tile[(ly + iy) * LDS_STRIDE + lx];
        const float4 q0 = rp[0], q1 = rp[1], q2 = rp[2], q3 = rp[3];

        // 11 shifted 4-wide windows — pure component renames, no VALU
        const float4 s0 = q0;
        const float4 s1 = make_float4(q0.y, q0.z, q0.w, q1.x);
        const float4 s2 = make_float4(q0.z, q0.w, q1.x, q1.y);
        const float4 s3 = make_float4(q0.w, q1.x, q1.y, q1.z);
        const float4 s4 = q1;
        const float4 s5 = make_float4(q1.y, q1.z, q1.w, q2.x);
        const float4 s6 = make_float4(q1.z, q1.w, q2.x, q2.y);
        const float4 s7 = make_float4(q1.w, q2.x, q2.y, q2.z);
        const float4 s8 = q2;
        const float4 s9 = make_float4(q2.y, q2.z, q2.w, q3.x);
        const float4 s10= make_float4(q2.z, q2.w, q3.x, q3.y);

        #define ROW(ACC, KY) do {                                   \
            const float* wr = w + (KY) * KSIZE;  /* literal offs */ \
            ACC = fma4(wr[0],  s0,  ACC); ACC = fma4(wr[1],  s1,  ACC); \
            ACC = fma4(wr[2],  s2,  ACC); ACC = fma4(wr[3],  s3,  ACC); \
            ACC = fma4(wr[4],  s4,  ACC); ACC = fma4(wr[5],  s5,  ACC); \
            ACC = fma4(wr[6],  s6,  ACC); ACC = fma4(wr[7],  s7,  ACC); \
            ACC = fma4(wr[8],  s8,  ACC); ACC = fma4(wr[9],  s9,  ACC); \
            ACC = fma4(wr[10], s10, ACC); } while (0)

        // iy is a constant after unroll -> these guards fold away
        if (iy - 0 >= 0 && iy - 0 <= 10) ROW(acc0, iy - 0);
        if (iy - 1 >= 0 && iy - 1 <= 10) ROW(acc1, iy - 1);
        if (iy - 2 >= 0 && iy - 2 <= 10) ROW(acc2, iy - 2);
        if (iy - 3 >= 0 && iy - 3 <= 10) ROW(acc3, iy - 3);
        #undef ROW
    }

    // ---- coalesced float4 stores
    float* ob = out + (size_t)blockIdx.z * IMG * IMG;
    const size_t base = (size_t)(tile_y0 + ly) * IMG + tile_x0 + lx;
    *(float4*)&ob[base + 0 * IMG] = acc0;
    *(float4*)&ob[base + 1 * IMG] = acc1;
    *(float4*)&ob[base + 2 * IMG] = acc2;
    *(float4*)&ob[base + 3 * IMG] = acc3;
}

extern "C" void kernel_launch(void* const* d_in, const int* in_sizes, int n_in,
                              void* d_out, int out_size, void* d_ws, size_t ws_size,
                              hipStream_t stream) {
    const float* x = (const float*)d_in[0];
    const float* w = (const float*)d_in[1];
    float* out = (float*)d_out;

    dim3 grid(IMG / TILE, IMG / TILE, 64);   // 16 x 16 x 64
    dim3 block(256);
    conv11_tile_kernel<<<grid, block, 0, stream>>>(x, w, out);
}

// Round 4
// 822.371 us; speedup vs baseline: 1.0020x; 1.0020x over previous
//
#include <hip/hip_runtime.h>

#define TILE 64
#define HALO 5
#define KSIZE 11
#define IN_TILE (TILE + 2 * HALO)   // 74
#define LDS_STRIDE 76               // rows 16B-aligned
#define IMG 1024

// min 8 waves/EU -> compiler must keep VGPR <= 64 (the occupancy cliff:
// waves/SIMD halve at vgpr=64; round 3's 68 VGPR cost 1.6x perf).
__global__ __launch_bounds__(256, 8)
void conv11_tile_kernel(const float* __restrict__ x,
                        const float* __restrict__ w,
                        float* __restrict__ out) {
    __shared__ float tile[IN_TILE * LDS_STRIDE];

    const int tid  = threadIdx.x;
    const int lane = tid & 63;
    const int wid  = tid >> 6;
    const int tx   = tid & 15;       // 16 threads across
    const int ty   = tid >> 4;       // 16 threads down
    const int tile_x0 = blockIdx.x * TILE;
    const int tile_y0 = blockIdx.y * TILE;
    const float* xb = x + (size_t)blockIdx.z * IMG * IMG;

    // ---- stage 74x74 (zero halo) into LDS: wave-per-row stripes, no divides
    for (int r = wid; r < IN_TILE; r += 4) {
        const int gy = tile_y0 + r - HALO;
        const bool rowok = (unsigned)gy < IMG;
        const int gx0 = tile_x0 - HALO + lane;
        float v0 = 0.0f;
        if (rowok && (unsigned)gx0 < IMG) v0 = xb[(size_t)gy * IMG + gx0];
        tile[r * LDS_STRIDE + lane] = v0;
        if (lane < IN_TILE - 64) {           // cols 64..73
            const int gx1 = gx0 + 64;
            float v1 = 0.0f;
            if (rowok && (unsigned)gx1 < IMG) v1 = xb[(size_t)gy * IMG + gx1];
            tile[r * LDS_STRIDE + lane + 64] = v1;
        }
    }
    __syncthreads();

    // ---- 4x4 outputs per thread. Only r[0..13] are live: 3x b128 + 1x b64.
    float acc[4][4] = {};
    const int ly = ty * 4;
    const int lx = tx * 4;

    #pragma unroll
    for (int iy = 0; iy < 14; ++iy) {
        const float* row = &tile[(ly + iy) * LDS_STRIDE + lx];
        const float4 q0 = *(const float4*)(row);
        const float4 q1 = *(const float4*)(row + 4);
        const float4 q2 = *(const float4*)(row + 8);
        const float2 q3 = *(const float2*)(row + 12);   // only 2 floats needed
        const float r[14] = {q0.x, q0.y, q0.z, q0.w, q1.x, q1.y, q1.z, q1.w,
                             q2.x, q2.y, q2.z, q2.w, q3.x, q3.y};
        #pragma unroll
        for (int oy = 0; oy < 4; ++oy) {
            const int ky = iy - oy;          // compile-time after unroll
            if (ky < 0 || ky > 10) continue; // folds away
            #pragma unroll
            for (int kx = 0; kx < KSIZE; ++kx) {
                const float wv = w[ky * KSIZE + kx];  // uniform -> s_load
                acc[oy][0] = fmaf(wv, r[kx + 0], acc[oy][0]);
                acc[oy][1] = fmaf(wv, r[kx + 1], acc[oy][1]);
                acc[oy][2] = fmaf(wv, r[kx + 2], acc[oy][2]);
                acc[oy][3] = fmaf(wv, r[kx + 3], acc[oy][3]);
            }
        }
    }

    // ---- coalesced float4 stores
    float* ob = out + (size_t)blockIdx.z * IMG * IMG;
    const size_t base = (size_t)(tile_y0 + ly) * IMG + tile_x0 + lx;
    #pragma unroll
    for (int oy = 0; oy < 4; ++oy) {
        *(float4*)&ob[base + (size_t)oy * IMG] =
            make_float4(acc[oy][0], acc[oy][1], acc[oy][2], acc[oy][3]);
    }
}

extern "C" void kernel_launch(void* const* d_in, const int* in_sizes, int n_in,
                              void* d_out, int out_size, void* d_ws, size_t ws_size,
                              hipStream_t stream) {
    const float* x = (const float*)d_in[0];
    const float* w = (const float*)d_in[1];
    float* out = (float*)d_out;

    dim3 grid(IMG / TILE, IMG / TILE, 64);   // 16 x 16 x 64
    dim3 block(256);
    conv11_tile_kernel<<<grid, block, 0, stream>>>(x, w, out);
}